// Round 7
// baseline (604.436 us; speedup 1.0000x reference)
//
#include <hip/hip_runtime.h>
#include <math.h>

// ---------------------------------------------------------------------------
// PinSageConv, round 7: bucket-partitioned edge aggregation.
//   gemm1    : n = relu(h @ q_w^T + q_b)   bf16 MFMA -> bf16   (unchanged)
//   bhist    : per-block LDS histogram over NB=ceil(ndst/128) buckets (dst>>7),
//              bucket-major table hist[b*G+g]  (G = partition blocks)
//   scan x3  : hierarchical exclusive scan of the NB*G bin table
//   part     : scatter edges into per-(bucket,block) bins -- each block writes
//              only its own ~37KB region => single-L2 lines, compact writeback
//              (round-6 k_scatter wrote 39.6MB HBM for a 4.8MB payload: every
//               random 8B store dirtied a 64B line shared across XCDs)
//   aggregate: one block per bucket; agg[128][128] f32 in LDS via ds_add_f32;
//              4 edges in flight/wave; epilogue /max(ws,1) -> z2 bf16
//   gemm2    : out = rownorm(relu([h_dst|z2] @ w_w^T + w_b)) -> f32 (unchanged)
// Edge payload: int2 { (dst_local<<17) | src , w }   (src < 2^17 = 131072)
// MFMA 16x16x32_bf16 (m89-verified); swapped (b,a) => lane&15 = out row.
// ---------------------------------------------------------------------------

typedef __attribute__((ext_vector_type(8))) short  short8;
typedef __attribute__((ext_vector_type(8))) __bf16 bf16x8;
typedef __attribute__((ext_vector_type(4))) float  f32x4;

#define MFMA16(a, b, c) __builtin_amdgcn_mfma_f32_16x16x32_bf16( \
    __builtin_bit_cast(bf16x8, (a)), __builtin_bit_cast(bf16x8, (b)), (c), 0, 0, 0)

__device__ __forceinline__ ushort f2bf(float x) {            // RNE f32->bf16
    unsigned u = __float_as_uint(x);
    return (ushort)((u + 0x7fffu + ((u >> 16) & 1u)) >> 16);
}
__device__ __forceinline__ float bfhi(unsigned p) { return __uint_as_float(p & 0xffff0000u); }
__device__ __forceinline__ float bflo(unsigned p) { return __uint_as_float(p << 16); }

__device__ __forceinline__ short8 cvt8(float4 v0, float4 v1) {
    ushort t[8] = { f2bf(v0.x), f2bf(v0.y), f2bf(v0.z), f2bf(v0.w),
                    f2bf(v1.x), f2bf(v1.y), f2bf(v1.z), f2bf(v1.w) };
    return *(short8*)t;
}

// ---------------- GEMM1: 512 thr, 128-row tile, A+B in LDS -----------------
__global__ __launch_bounds__(512) void k_gemm1(const float* __restrict__ h,
    const float* __restrict__ qw, const float* __restrict__ qb,
    ushort* __restrict__ nout, int nrows)
{
    __shared__ __align__(16) ushort aL[128 * 128];
    __shared__ __align__(16) ushort bL[128 * 128];
    const int tid = threadIdx.x;
    const int rb  = blockIdx.x * 128;
    const int rr = tid >> 4, sl = tid & 15;

    #pragma unroll
    for (int rg = 0; rg < 4; ++rg) {
        int row = rg * 32 + rr, gr = rb + row;
        float4 a0 = make_float4(0.f,0.f,0.f,0.f), a1 = a0;
        if (gr < nrows) {
            a0 = *(const float4*)&h[(size_t)gr * 128 + sl * 8];
            a1 = *(const float4*)&h[(size_t)gr * 128 + sl * 8 + 4];
        }
        *(short8*)&aL[row * 128 + (sl ^ (row & 7)) * 8] = cvt8(a0, a1);
        float4 b0 = *(const float4*)&qw[row * 128 + sl * 8];
        float4 b1 = *(const float4*)&qw[row * 128 + sl * 8 + 4];
        *(short8*)&bL[row * 128 + (sl ^ (row & 7)) * 8] = cvt8(b0, b1);
    }
    __syncthreads();

    const int w = tid >> 6, l = tid & 63;
    const int lr = l & 15, lk = l >> 4;
    const int row = w * 16 + lr;

    short8 a[4];
    #pragma unroll
    for (int ks = 0; ks < 4; ++ks)
        a[ks] = *(const short8*)&aL[row * 128 + ((ks * 4 + lk) ^ (lr & 7)) * 8];

    f32x4 acc[8];
    #pragma unroll
    for (int nt = 0; nt < 8; ++nt) acc[nt] = (f32x4){0.f, 0.f, 0.f, 0.f};

    #pragma unroll
    for (int nt = 0; nt < 8; ++nt)
        #pragma unroll
        for (int ks = 0; ks < 4; ++ks) {
            short8 b = *(const short8*)&bL[(nt * 16 + lr) * 128 + ((ks * 4 + lk) ^ (lr & 7)) * 8];
            acc[nt] = MFMA16(b, a[ks], acc[nt]);   // swapped: lane&15 = row
        }

    const int gr = rb + row;
    if (gr < nrows) {
        #pragma unroll
        for (int nt = 0; nt < 8; ++nt) {
            float4 bv = *(const float4*)&qb[nt * 16 + lk * 4];
            ushort t[4];
            t[0] = f2bf(fmaxf(acc[nt][0] + bv.x, 0.f));
            t[1] = f2bf(fmaxf(acc[nt][1] + bv.y, 0.f));
            t[2] = f2bf(fmaxf(acc[nt][2] + bv.z, 0.f));
            t[3] = f2bf(fmaxf(acc[nt][3] + bv.w, 0.f));
            *(ushort4*)&nout[(size_t)gr * 128 + nt * 16 + lk * 4] = *(ushort4*)t;
        }
    }
}

// ---------------- bucket histogram (per-block LDS, bucket-major table) -----
__global__ __launch_bounds__(256) void k_bhist(const int* __restrict__ dst,
    int* __restrict__ hist, int nedges, int nb)
{
    __shared__ int hl[512];
    const int g = blockIdx.x, tid = threadIdx.x, G = gridDim.x;
    for (int b = tid; b < nb; b += 256) hl[b] = 0;
    __syncthreads();
    const int chunk = (nedges + G - 1) / G;
    const int e0 = g * chunk, e1 = min(e0 + chunk, nedges);
    for (int e = e0 + tid; e < e1; e += 256)
        atomicAdd(&hl[dst[e] >> 7], 1);
    __syncthreads();
    for (int b = tid; b < nb; b += 256) hist[b * G + g] = hl[b];
}

// ---------------- hierarchical exclusive scan over nb*G bins ---------------
__global__ __launch_bounds__(1024) void k_scan_blk(const int* __restrict__ counts,
    int* __restrict__ offs, int* __restrict__ partials, int n)
{
    __shared__ int wtot[16];
    const int tid = threadIdx.x, lane = tid & 63, wv = tid >> 6;
    const int idx = blockIdx.x * 1024 + tid;
    int v = (idx < n) ? counts[idx] : 0;
    int x = v;
    #pragma unroll
    for (int off = 1; off < 64; off <<= 1) {
        int y = __shfl_up(x, off);
        if (lane >= off) x += y;
    }
    if (lane == 63) wtot[wv] = x;
    __syncthreads();
    if (tid == 0) {
        int r = 0;
        #pragma unroll
        for (int q = 0; q < 16; ++q) { int t = wtot[q]; wtot[q] = r; r += t; }
    }
    __syncthreads();
    if (idx < n) offs[idx] = wtot[wv] + x - v;
    if (tid == 1023) partials[blockIdx.x] = wtot[15] + x;
}

__global__ void k_scan_part(int* __restrict__ partials, int nb)
{
    const int lane = threadIdx.x;
    int v = (lane < nb) ? partials[lane] : 0;
    int x = v;
    #pragma unroll
    for (int off = 1; off < 64; off <<= 1) {
        int y = __shfl_up(x, off);
        if (lane >= off) x += y;
    }
    if (lane < nb) partials[lane] = x - v;
}

__global__ __launch_bounds__(1024) void k_scan_add(int* __restrict__ offs,
    const int* __restrict__ partials, int n)
{
    const int idx = blockIdx.x * 1024 + threadIdx.x;
    if (idx < n) offs[idx] += partials[blockIdx.x];
}

// ---------------- partition: scatter into per-(bucket,block) bins ----------
__global__ __launch_bounds__(256) void k_part(const int* __restrict__ src,
    const int* __restrict__ dst, const float* __restrict__ w,
    const int* __restrict__ binoff, int2* __restrict__ eb, int nedges, int nb)
{
    __shared__ int cur[512];
    const int g = blockIdx.x, tid = threadIdx.x, G = gridDim.x;
    for (int b = tid; b < nb; b += 256) cur[b] = binoff[b * G + g];
    __syncthreads();
    const int chunk = (nedges + G - 1) / G;
    const int e0 = g * chunk, e1 = min(e0 + chunk, nedges);
    for (int e = e0 + tid; e < e1; e += 256) {
        int d = dst[e];
        int pos = atomicAdd(&cur[d >> 7], 1);                // LDS cursor
        eb[pos] = make_int2(((d & 127) << 17) | src[e], __float_as_int(w[e]));
    }
}

// ---------------- aggregate: block = 1 bucket (128 dst rows) in LDS --------
__global__ __launch_bounds__(256) void k_aggregate(const ushort* __restrict__ nsrc,
    const int2* __restrict__ eb, const int* __restrict__ binoff,
    ushort* __restrict__ z2, int ndst, int nedges, int G)
{
    __shared__ float agg[128 * 128];     // 64 KB
    __shared__ float wsum[128];
    const int tid = threadIdx.x;
    const int b   = blockIdx.x;

    for (int i = tid * 4; i < 128 * 128; i += 1024)
        *(float4*)&agg[i] = make_float4(0.f, 0.f, 0.f, 0.f);
    if (tid < 128) wsum[tid] = 0.f;
    __syncthreads();

    const int j0 = binoff[b * G];
    const int j1 = (b == gridDim.x - 1) ? nedges : binoff[(b + 1) * G];
    const int wv = tid >> 6, lane = tid & 63;

    for (int j = j0 + wv * 4; j < j1; j += 16) {            // 4 waves x 4 edges
        int2 ew[4]; unsigned p[4];
        #pragma unroll
        for (int k = 0; k < 4; ++k)
            if (j + k < j1) ew[k] = eb[j + k];
        #pragma unroll
        for (int k = 0; k < 4; ++k)
            if (j + k < j1)
                p[k] = *(const unsigned*)&nsrc[(size_t)(ew[k].x & 0x1FFFF) * 128 + lane * 2];
        #pragma unroll
        for (int k = 0; k < 4; ++k)
            if (j + k < j1) {
                int dl = ew[k].x >> 17;
                float we = __int_as_float(ew[k].y);
                atomicAdd(&agg[dl * 128 + lane * 2],     bflo(p[k]) * we);
                atomicAdd(&agg[dl * 128 + lane * 2 + 1], bfhi(p[k]) * we);
                if (lane == 0) atomicAdd(&wsum[dl], we);
            }
    }
    __syncthreads();

    const int r = tid >> 1, c0 = (tid & 1) * 64;
    const int gr = b * 128 + r;
    if (gr < ndst) {
        float inv = 1.f / fmaxf(wsum[r], 1.f);
        #pragma unroll
        for (int c = 0; c < 64; c += 8) {
            ushort t8[8];
            #pragma unroll
            for (int i = 0; i < 8; ++i)
                t8[i] = f2bf(agg[r * 128 + c0 + c + i] * inv);
            *(short8*)&z2[(size_t)gr * 128 + c0 + c] = *(short8*)t8;
        }
    }
}

// ---------------- GEMM2 + rownorm: 512 thr, 128-row tile, 2 K-phases -------
__global__ __launch_bounds__(512) void k_gemm2(const float* __restrict__ h,
    const ushort* __restrict__ z2, const float* __restrict__ ww,
    const float* __restrict__ wb, float* __restrict__ out, int nrows)
{
    __shared__ __align__(16) ushort aL[128 * 128];
    __shared__ __align__(16) ushort bL[128 * 128];
    const int tid = threadIdx.x;
    const int rb  = blockIdx.x * 128;
    const int rr = tid >> 4, sl = tid & 15;

    const int w = tid >> 6, l = tid & 63;
    const int lr = l & 15, lk = l >> 4;
    const int row = w * 16 + lr;

    f32x4 acc[8];
    #pragma unroll
    for (int nt = 0; nt < 8; ++nt) acc[nt] = (f32x4){0.f, 0.f, 0.f, 0.f};

    #pragma unroll
    for (int ph = 0; ph < 2; ++ph) {
        if (ph) __syncthreads();
        #pragma unroll
        for (int rg = 0; rg < 4; ++rg) {
            int r2 = rg * 32 + rr, gr = rb + r2;
            short8 av = (short8){0,0,0,0,0,0,0,0};
            if (gr < nrows) {
                if (ph == 0) {
                    float4 a0 = *(const float4*)&h[(size_t)gr * 128 + sl * 8];
                    float4 a1 = *(const float4*)&h[(size_t)gr * 128 + sl * 8 + 4];
                    av = cvt8(a0, a1);
                } else {
                    av = *(const short8*)&z2[(size_t)gr * 128 + sl * 8];
                }
            }
            *(short8*)&aL[r2 * 128 + (sl ^ (r2 & 7)) * 8] = av;
            float4 b0 = *(const float4*)&ww[r2 * 256 + ph * 128 + sl * 8];
            float4 b1 = *(const float4*)&ww[r2 * 256 + ph * 128 + sl * 8 + 4];
            *(short8*)&bL[r2 * 128 + (sl ^ (r2 & 7)) * 8] = cvt8(b0, b1);
        }
        __syncthreads();

        short8 a[4];
        #pragma unroll
        for (int ks = 0; ks < 4; ++ks)
            a[ks] = *(const short8*)&aL[row * 128 + ((ks * 4 + lk) ^ (lr & 7)) * 8];

        #pragma unroll
        for (int nt = 0; nt < 8; ++nt)
            #pragma unroll
            for (int ks = 0; ks < 4; ++ks) {
                short8 b = *(const short8*)&bL[(nt * 16 + lr) * 128 + ((ks * 4 + lk) ^ (lr & 7)) * 8];
                acc[nt] = MFMA16(b, a[ks], acc[nt]);
            }
    }

    float val[8][4];
    float ss = 0.f;
    #pragma unroll
    for (int nt = 0; nt < 8; ++nt) {
        float4 bv = *(const float4*)&wb[nt * 16 + lk * 4];
        #pragma unroll
        for (int v = 0; v < 4; ++v) {
            float x = acc[nt][v] + ((const float*)&bv)[v];
            x = fmaxf(x, 0.f);
            val[nt][v] = x;
            ss = fmaf(x, x, ss);
        }
    }
    ss += __shfl_xor(ss, 16);
    ss += __shfl_xor(ss, 32);
    float nr = sqrtf(ss);
    nr = (nr == 0.f) ? 1.f : nr;
    float inv = 1.f / nr;

    const int gr = rb + row;
    if (gr < nrows) {
        #pragma unroll
        for (int nt = 0; nt < 8; ++nt) {
            float4 o;
            o.x = val[nt][0] * inv; o.y = val[nt][1] * inv;
            o.z = val[nt][2] * inv; o.w = val[nt][3] * inv;
            *(float4*)&out[(size_t)gr * 128 + nt * 16 + lk * 4] = o;
        }
    }
}

// ---------------------------------------------------------------------------
extern "C" void kernel_launch(void* const* d_in, const int* in_sizes, int n_in,
                              void* d_out, int out_size, void* d_ws, size_t ws_size,
                              hipStream_t stream)
{
    const float* h   = (const float*)d_in[0];
    const float* wts = (const float*)d_in[1];
    const int*   src = (const int*)d_in[2];
    const int*   dst = (const int*)d_in[3];
    const float* qw  = (const float*)d_in[5];
    const float* qb  = (const float*)d_in[6];
    const float* www = (const float*)d_in[7];
    const float* wb  = (const float*)d_in[8];
    float* out = (float*)d_out;

    const int n_src   = in_sizes[0] / 128;
    const int n_edges = in_sizes[1];
    const int n_dst   = out_size / 128;

    const int G  = 128;                           // partition blocks
    const int NB = (n_dst + 127) / 128;           // buckets (391)
    const int NBINS = NB * G;                     // bin table size (50048)

    // workspace layout
    ushort* nbuf   = (ushort*)d_ws;                          // n_src*128 bf16
    ushort* z2     = nbuf + (size_t)n_src * 128;             // n_dst*128 bf16
    int2*   eb     = (int2*)(z2 + (size_t)n_dst * 128);      // n_edges int2
    int*    hist   = (int*)(eb + n_edges);                   // NBINS
    int*    binoff = hist + NBINS;                           // NBINS
    int*    parts  = binoff + NBINS;                         // <= 64

    const int t1 = (n_src + 127) / 128;
    k_gemm1<<<t1, 512, 0, stream>>>(h, qw, qb, nbuf, n_src);

    k_bhist<<<G, 256, 0, stream>>>(dst, hist, n_edges, NB);

    const int nbs = (NBINS + 1023) / 1024;
    k_scan_blk<<<nbs, 1024, 0, stream>>>(hist, binoff, parts, NBINS);
    k_scan_part<<<1, 64, 0, stream>>>(parts, nbs);
    k_scan_add<<<nbs, 1024, 0, stream>>>(binoff, parts, NBINS);

    k_part<<<G, 256, 0, stream>>>(src, dst, wts, binoff, eb, n_edges, NB);

    k_aggregate<<<NB, 256, 0, stream>>>(nbuf, eb, binoff, z2, n_dst, n_edges, G);

    const int t2 = (n_dst + 127) / 128;
    k_gemm2<<<t2, 512, 0, stream>>>(h, z2, www, wb, out, n_dst);
}

// Round 8
// 107.358 us; speedup vs baseline: 5.6301x; 5.6301x over previous
//
#include <hip/hip_runtime.h>
#include <math.h>

// ---------------------------------------------------------------------------
// PinSageConv, round 8: R6 GEMMs + R5 gather + R7 compact partition + new
// per-bucket sort (replaces both R6's k_scatter [39.6MB HBM write-amp] and
// R7's k_aggregate [76.8M LDS atomics = 535us -- reverted]).
//   gemm1 : n = relu(h @ q_w^T + q_b)   bf16 MFMA -> bf16
//   bhist : per-block hist over NB buckets (dst>>7), bucket-major hist[b*G+g]
//   scan3 : hierarchical exclusive scan of NB*G bin table
//   part  : scatter edges into per-(bucket,block) bins (compact 37KB/block)
//   bsort : block=bucket: LDS 128-ctr hist+scan -> offs[dst]; cursor-scatter
//           into dst-sorted ebs (writes stay in own 12KB window)
//   gather: wave=dst row, 4 edges in flight, 16B lane slices  -> z2 bf16
//   gemm2 : out = rownorm(relu([h_dst|z2] @ w_w^T + w_b)) -> f32
// Edge payload eb: int2{ (dst_local<<17)|src , w };  ebs: int2{ src, w }.
// MFMA 16x16x32_bf16 (m89-verified); swapped (b,a) => lane&15 = out row.
// ---------------------------------------------------------------------------

typedef __attribute__((ext_vector_type(8))) short  short8;
typedef __attribute__((ext_vector_type(8))) __bf16 bf16x8;
typedef __attribute__((ext_vector_type(4))) float  f32x4;

#define MFMA16(a, b, c) __builtin_amdgcn_mfma_f32_16x16x32_bf16( \
    __builtin_bit_cast(bf16x8, (a)), __builtin_bit_cast(bf16x8, (b)), (c), 0, 0, 0)

__device__ __forceinline__ ushort f2bf(float x) {            // RNE f32->bf16
    unsigned u = __float_as_uint(x);
    return (ushort)((u + 0x7fffu + ((u >> 16) & 1u)) >> 16);
}
__device__ __forceinline__ float bfhi(unsigned p) { return __uint_as_float(p & 0xffff0000u); }
__device__ __forceinline__ float bflo(unsigned p) { return __uint_as_float(p << 16); }

__device__ __forceinline__ short8 cvt8(float4 v0, float4 v1) {
    ushort t[8] = { f2bf(v0.x), f2bf(v0.y), f2bf(v0.z), f2bf(v0.w),
                    f2bf(v1.x), f2bf(v1.y), f2bf(v1.z), f2bf(v1.w) };
    return *(short8*)t;
}

// ---------------- GEMM1: 512 thr, 128-row tile, A+B in LDS -----------------
__global__ __launch_bounds__(512) void k_gemm1(const float* __restrict__ h,
    const float* __restrict__ qw, const float* __restrict__ qb,
    ushort* __restrict__ nout, int nrows)
{
    __shared__ __align__(16) ushort aL[128 * 128];
    __shared__ __align__(16) ushort bL[128 * 128];
    const int tid = threadIdx.x;
    const int rb  = blockIdx.x * 128;
    const int rr = tid >> 4, sl = tid & 15;

    #pragma unroll
    for (int rg = 0; rg < 4; ++rg) {
        int row = rg * 32 + rr, gr = rb + row;
        float4 a0 = make_float4(0.f,0.f,0.f,0.f), a1 = a0;
        if (gr < nrows) {
            a0 = *(const float4*)&h[(size_t)gr * 128 + sl * 8];
            a1 = *(const float4*)&h[(size_t)gr * 128 + sl * 8 + 4];
        }
        *(short8*)&aL[row * 128 + (sl ^ (row & 7)) * 8] = cvt8(a0, a1);
        float4 b0 = *(const float4*)&qw[row * 128 + sl * 8];
        float4 b1 = *(const float4*)&qw[row * 128 + sl * 8 + 4];
        *(short8*)&bL[row * 128 + (sl ^ (row & 7)) * 8] = cvt8(b0, b1);
    }
    __syncthreads();

    const int w = tid >> 6, l = tid & 63;
    const int lr = l & 15, lk = l >> 4;
    const int row = w * 16 + lr;

    short8 a[4];
    #pragma unroll
    for (int ks = 0; ks < 4; ++ks)
        a[ks] = *(const short8*)&aL[row * 128 + ((ks * 4 + lk) ^ (lr & 7)) * 8];

    f32x4 acc[8];
    #pragma unroll
    for (int nt = 0; nt < 8; ++nt) acc[nt] = (f32x4){0.f, 0.f, 0.f, 0.f};

    #pragma unroll
    for (int nt = 0; nt < 8; ++nt)
        #pragma unroll
        for (int ks = 0; ks < 4; ++ks) {
            short8 b = *(const short8*)&bL[(nt * 16 + lr) * 128 + ((ks * 4 + lk) ^ (lr & 7)) * 8];
            acc[nt] = MFMA16(b, a[ks], acc[nt]);   // swapped: lane&15 = row
        }

    const int gr = rb + row;
    if (gr < nrows) {
        #pragma unroll
        for (int nt = 0; nt < 8; ++nt) {
            float4 bv = *(const float4*)&qb[nt * 16 + lk * 4];
            ushort t[4];
            t[0] = f2bf(fmaxf(acc[nt][0] + bv.x, 0.f));
            t[1] = f2bf(fmaxf(acc[nt][1] + bv.y, 0.f));
            t[2] = f2bf(fmaxf(acc[nt][2] + bv.z, 0.f));
            t[3] = f2bf(fmaxf(acc[nt][3] + bv.w, 0.f));
            *(ushort4*)&nout[(size_t)gr * 128 + nt * 16 + lk * 4] = *(ushort4*)t;
        }
    }
}

// ---------------- bucket histogram (per-block LDS, bucket-major table) -----
__global__ __launch_bounds__(256) void k_bhist(const int* __restrict__ dst,
    int* __restrict__ hist, int nedges, int nb)
{
    __shared__ int hl[512];
    const int g = blockIdx.x, tid = threadIdx.x, G = gridDim.x;
    for (int b = tid; b < nb; b += 256) hl[b] = 0;
    __syncthreads();
    const int chunk = (nedges + G - 1) / G;
    const int e0 = g * chunk, e1 = min(e0 + chunk, nedges);
    for (int e = e0 + tid; e < e1; e += 256)
        atomicAdd(&hl[dst[e] >> 7], 1);
    __syncthreads();
    for (int b = tid; b < nb; b += 256) hist[b * G + g] = hl[b];
}

// ---------------- hierarchical exclusive scan over nb*G bins ---------------
__global__ __launch_bounds__(1024) void k_scan_blk(const int* __restrict__ counts,
    int* __restrict__ offs, int* __restrict__ partials, int n)
{
    __shared__ int wtot[16];
    const int tid = threadIdx.x, lane = tid & 63, wv = tid >> 6;
    const int idx = blockIdx.x * 1024 + tid;
    int v = (idx < n) ? counts[idx] : 0;
    int x = v;
    #pragma unroll
    for (int off = 1; off < 64; off <<= 1) {
        int y = __shfl_up(x, off);
        if (lane >= off) x += y;
    }
    if (lane == 63) wtot[wv] = x;
    __syncthreads();
    if (tid == 0) {
        int r = 0;
        #pragma unroll
        for (int q = 0; q < 16; ++q) { int t = wtot[q]; wtot[q] = r; r += t; }
    }
    __syncthreads();
    if (idx < n) offs[idx] = wtot[wv] + x - v;
    if (tid == 1023) partials[blockIdx.x] = wtot[15] + x;
}

__global__ void k_scan_part(int* __restrict__ partials, int nb)
{
    const int lane = threadIdx.x;
    int v = (lane < nb) ? partials[lane] : 0;
    int x = v;
    #pragma unroll
    for (int off = 1; off < 64; off <<= 1) {
        int y = __shfl_up(x, off);
        if (lane >= off) x += y;
    }
    if (lane < nb) partials[lane] = x - v;
}

__global__ __launch_bounds__(1024) void k_scan_add(int* __restrict__ offs,
    const int* __restrict__ partials, int n)
{
    const int idx = blockIdx.x * 1024 + threadIdx.x;
    if (idx < n) offs[idx] += partials[blockIdx.x];
}

// ---------------- partition: scatter into per-(bucket,block) bins ----------
__global__ __launch_bounds__(256) void k_part(const int* __restrict__ src,
    const int* __restrict__ dst, const float* __restrict__ w,
    const int* __restrict__ binoff, int2* __restrict__ eb, int nedges, int nb)
{
    __shared__ int cur[512];
    const int g = blockIdx.x, tid = threadIdx.x, G = gridDim.x;
    for (int b = tid; b < nb; b += 256) cur[b] = binoff[b * G + g];
    __syncthreads();
    const int chunk = (nedges + G - 1) / G;
    const int e0 = g * chunk, e1 = min(e0 + chunk, nedges);
    for (int e = e0 + tid; e < e1; e += 256) {
        int d = dst[e];
        int pos = atomicAdd(&cur[d >> 7], 1);                // LDS cursor
        eb[pos] = make_int2(((d & 127) << 17) | src[e], __float_as_int(w[e]));
    }
}

// ---------------- bucket sort: block = bucket, dst-sorted output -----------
__global__ __launch_bounds__(256) void k_bsort(const int2* __restrict__ eb,
    const int* __restrict__ binoff, int2* __restrict__ ebs,
    int* __restrict__ offs, int ndst, int nedges, int G, int NB)
{
    __shared__ int cnt[128];
    __shared__ int cur[128];
    const int b = blockIdx.x, tid = threadIdx.x;
    const int j0 = binoff[b * G];
    const int j1 = (b == NB - 1) ? nedges : binoff[(b + 1) * G];

    if (tid < 128) cnt[tid] = 0;
    __syncthreads();
    for (int j = j0 + tid; j < j1; j += 256)
        atomicAdd(&cnt[eb[j].x >> 17], 1);
    __syncthreads();

    if (tid < 64) {                    // wave 0: exclusive scan of 128 counters
        int a0 = cnt[tid];
        int x = a0;
        #pragma unroll
        for (int off = 1; off < 64; off <<= 1) {
            int y = __shfl_up(x, off);
            if (tid >= off) x += y;
        }
        int sum0 = __shfl(x, 63);
        int a1 = cnt[64 + tid];
        int x1 = a1;
        #pragma unroll
        for (int off = 1; off < 64; off <<= 1) {
            int y = __shfl_up(x1, off);
            if (tid >= off) x1 += y;
        }
        cur[tid]      = j0 + x - a0;
        cur[64 + tid] = j0 + sum0 + x1 - a1;
    }
    __syncthreads();

    if (tid < 128) {
        int gr = b * 128 + tid;
        if (gr < ndst) offs[gr] = cur[tid];
    }
    if (b == NB - 1 && tid == 0) offs[ndst] = nedges;
    __syncthreads();

    for (int j = j0 + tid; j < j1; j += 256) {
        int2 e = eb[j];
        int pos = atomicAdd(&cur[e.x >> 17], 1);
        ebs[pos] = make_int2(e.x & 0x1FFFF, e.y);
    }
}

// ---------------- gather: wave = 1 dst row, 4 edges in flight --------------
__global__ __launch_bounds__(256) void k_gather(const ushort* __restrict__ nsrc,
    const int* __restrict__ offs, const int2* __restrict__ eSrcW,
    ushort* __restrict__ z2, int ndst)
{
    const int wave = (blockIdx.x * 256 + threadIdx.x) >> 6;
    const int lane = threadIdx.x & 63;
    const int g = lane >> 4, s = lane & 15;
    if (wave >= ndst) return;
    const int j0 = offs[wave], j1 = offs[wave + 1];

    float acc[8] = {0.f,0.f,0.f,0.f,0.f,0.f,0.f,0.f};
    float ws = 0.f;

    for (int j = j0 + g; j < j1; j += 4) {
        int2 ew = eSrcW[j];
        float we = __int_as_float(ew.y);
        short8 rv = *(const short8*)&nsrc[(size_t)ew.x * 128 + s * 8];
        uint4 p = __builtin_bit_cast(uint4, rv);
        acc[0] = fmaf(bflo(p.x), we, acc[0]);
        acc[1] = fmaf(bfhi(p.x), we, acc[1]);
        acc[2] = fmaf(bflo(p.y), we, acc[2]);
        acc[3] = fmaf(bfhi(p.y), we, acc[3]);
        acc[4] = fmaf(bflo(p.z), we, acc[4]);
        acc[5] = fmaf(bfhi(p.z), we, acc[5]);
        acc[6] = fmaf(bflo(p.w), we, acc[6]);
        acc[7] = fmaf(bfhi(p.w), we, acc[7]);
        ws += we;
    }

    #pragma unroll
    for (int i = 0; i < 8; ++i) {
        acc[i] += __shfl_xor(acc[i], 16);
        acc[i] += __shfl_xor(acc[i], 32);
    }
    ws += __shfl_xor(ws, 16);
    ws += __shfl_xor(ws, 32);

    if (g == 0) {
        float inv = 1.f / fmaxf(ws, 1.f);
        ushort t[8];
        #pragma unroll
        for (int i = 0; i < 8; ++i) t[i] = f2bf(acc[i] * inv);
        *(short8*)&z2[(size_t)wave * 128 + s * 8] = *(short8*)t;
    }
}

// ---------------- GEMM2 + rownorm: 512 thr, 128-row tile, 2 K-phases -------
__global__ __launch_bounds__(512) void k_gemm2(const float* __restrict__ h,
    const ushort* __restrict__ z2, const float* __restrict__ ww,
    const float* __restrict__ wb, float* __restrict__ out, int nrows)
{
    __shared__ __align__(16) ushort aL[128 * 128];
    __shared__ __align__(16) ushort bL[128 * 128];
    const int tid = threadIdx.x;
    const int rb  = blockIdx.x * 128;
    const int rr = tid >> 4, sl = tid & 15;

    const int w = tid >> 6, l = tid & 63;
    const int lr = l & 15, lk = l >> 4;
    const int row = w * 16 + lr;

    f32x4 acc[8];
    #pragma unroll
    for (int nt = 0; nt < 8; ++nt) acc[nt] = (f32x4){0.f, 0.f, 0.f, 0.f};

    #pragma unroll
    for (int ph = 0; ph < 2; ++ph) {
        if (ph) __syncthreads();
        #pragma unroll
        for (int rg = 0; rg < 4; ++rg) {
            int r2 = rg * 32 + rr, gr = rb + r2;
            short8 av = (short8){0,0,0,0,0,0,0,0};
            if (gr < nrows) {
                if (ph == 0) {
                    float4 a0 = *(const float4*)&h[(size_t)gr * 128 + sl * 8];
                    float4 a1 = *(const float4*)&h[(size_t)gr * 128 + sl * 8 + 4];
                    av = cvt8(a0, a1);
                } else {
                    av = *(const short8*)&z2[(size_t)gr * 128 + sl * 8];
                }
            }
            *(short8*)&aL[r2 * 128 + (sl ^ (r2 & 7)) * 8] = av;
            float4 b0 = *(const float4*)&ww[r2 * 256 + ph * 128 + sl * 8];
            float4 b1 = *(const float4*)&ww[r2 * 256 + ph * 128 + sl * 8 + 4];
            *(short8*)&bL[r2 * 128 + (sl ^ (r2 & 7)) * 8] = cvt8(b0, b1);
        }
        __syncthreads();

        short8 a[4];
        #pragma unroll
        for (int ks = 0; ks < 4; ++ks)
            a[ks] = *(const short8*)&aL[row * 128 + ((ks * 4 + lk) ^ (lr & 7)) * 8];

        #pragma unroll
        for (int nt = 0; nt < 8; ++nt)
            #pragma unroll
            for (int ks = 0; ks < 4; ++ks) {
                short8 b = *(const short8*)&bL[(nt * 16 + lr) * 128 + ((ks * 4 + lk) ^ (lr & 7)) * 8];
                acc[nt] = MFMA16(b, a[ks], acc[nt]);
            }
    }

    float val[8][4];
    float ss = 0.f;
    #pragma unroll
    for (int nt = 0; nt < 8; ++nt) {
        float4 bv = *(const float4*)&wb[nt * 16 + lk * 4];
        #pragma unroll
        for (int v = 0; v < 4; ++v) {
            float x = acc[nt][v] + ((const float*)&bv)[v];
            x = fmaxf(x, 0.f);
            val[nt][v] = x;
            ss = fmaf(x, x, ss);
        }
    }
    ss += __shfl_xor(ss, 16);
    ss += __shfl_xor(ss, 32);
    float nr = sqrtf(ss);
    nr = (nr == 0.f) ? 1.f : nr;
    float inv = 1.f / nr;

    const int gr = rb + row;
    if (gr < nrows) {
        #pragma unroll
        for (int nt = 0; nt < 8; ++nt) {
            float4 o;
            o.x = val[nt][0] * inv; o.y = val[nt][1] * inv;
            o.z = val[nt][2] * inv; o.w = val[nt][3] * inv;
            *(float4*)&out[(size_t)gr * 128 + nt * 16 + lk * 4] = o;
        }
    }
}

// ---------------------------------------------------------------------------
extern "C" void kernel_launch(void* const* d_in, const int* in_sizes, int n_in,
                              void* d_out, int out_size, void* d_ws, size_t ws_size,
                              hipStream_t stream)
{
    const float* h   = (const float*)d_in[0];
    const float* wts = (const float*)d_in[1];
    const int*   src = (const int*)d_in[2];
    const int*   dst = (const int*)d_in[3];
    const float* qw  = (const float*)d_in[5];
    const float* qb  = (const float*)d_in[6];
    const float* www = (const float*)d_in[7];
    const float* wb  = (const float*)d_in[8];
    float* out = (float*)d_out;

    const int n_src   = in_sizes[0] / 128;
    const int n_edges = in_sizes[1];
    const int n_dst   = out_size / 128;

    const int G  = 128;                           // partition blocks
    const int NB = (n_dst + 127) / 128;           // buckets (391)
    const int NBINS = NB * G;                     // bin table (50048)

    // workspace layout
    ushort* nbuf   = (ushort*)d_ws;                          // n_src*128 bf16
    ushort* z2     = nbuf + (size_t)n_src * 128;             // n_dst*128 bf16
    int2*   eb     = (int2*)(z2 + (size_t)n_dst * 128);      // n_edges int2
    int2*   ebs    = eb + n_edges;                           // n_edges int2
    int*    hist   = (int*)(ebs + n_edges);                  // NBINS
    int*    binoff = hist + NBINS;                           // NBINS
    int*    offs   = binoff + NBINS;                         // n_dst + 1
    int*    parts  = offs + n_dst + 2;                       // <= 64

    const int t1 = (n_src + 127) / 128;
    k_gemm1<<<t1, 512, 0, stream>>>(h, qw, qb, nbuf, n_src);

    k_bhist<<<G, 256, 0, stream>>>(dst, hist, n_edges, NB);

    const int nbs = (NBINS + 1023) / 1024;
    k_scan_blk<<<nbs, 1024, 0, stream>>>(hist, binoff, parts, NBINS);
    k_scan_part<<<1, 64, 0, stream>>>(parts, nbs);
    k_scan_add<<<nbs, 1024, 0, stream>>>(binoff, parts, NBINS);

    k_part<<<G, 256, 0, stream>>>(src, dst, wts, binoff, eb, n_edges, NB);

    k_bsort<<<NB, 256, 0, stream>>>(eb, binoff, ebs, offs, n_dst, n_edges, G, NB);

    const int gblocks = (n_dst + 3) / 4;
    k_gather<<<gblocks, 256, 0, stream>>>(nbuf, offs, ebs, z2, n_dst);

    const int t2 = (n_dst + 127) / 128;
    k_gemm2<<<t2, 512, 0, stream>>>(h, z2, www, wb, out, n_dst);
}

// Round 9
// 100.280 us; speedup vs baseline: 6.0275x; 1.0706x over previous
//
#include <hip/hip_runtime.h>
#include <math.h>

// ---------------------------------------------------------------------------
// PinSageConv, round 9: fusion pass.  6 kernels (was 9).
//   gemm1+bhist : n = relu(h @ q_w^T + q_b) (blocks 0..t1) || per-block bucket
//                 histogram over NB=ceil(ndst/64) buckets, dst>>6 (blocks t1..)
//   scan_blk    : per-1024-chunk exclusive scan of NB*G bin table
//   scan_part   : 1 block, 128 thr: exclusive scan of <=128 chunk totals
//                 (scan_add DELETED: consumers apply binoff0[i]+parts[i>>10])
//   part        : scatter edges into per-(bucket,block) bins (compact windows)
//   bsort_gather: block=bucket(64 dst rows): sort ~768-edge contiguous run
//                 into LDS (els[4096], 32KB), then gather rows from LDS edges
//                 -> z2 bf16.  (ebs/offs global round-trip DELETED.)
//   gemm2       : out = rownorm(relu([h_dst|z2] @ w_w^T + w_b)) -> f32
// Edge payload eb: int2{ (dst&63)<<17 | src , w }  (src < 2^17)
// MFMA 16x16x32_bf16 (m89-verified); swapped (b,a) => lane&15 = out row.
// ---------------------------------------------------------------------------

typedef __attribute__((ext_vector_type(8))) short  short8;
typedef __attribute__((ext_vector_type(8))) __bf16 bf16x8;
typedef __attribute__((ext_vector_type(4))) float  f32x4;

#define MFMA16(a, b, c) __builtin_amdgcn_mfma_f32_16x16x32_bf16( \
    __builtin_bit_cast(bf16x8, (a)), __builtin_bit_cast(bf16x8, (b)), (c), 0, 0, 0)

#define EDGE_CAP 4096   // LDS edge buffer per bucket (mean 768, ~46 sigma head)

__device__ __forceinline__ ushort f2bf(float x) {            // RNE f32->bf16
    unsigned u = __float_as_uint(x);
    return (ushort)((u + 0x7fffu + ((u >> 16) & 1u)) >> 16);
}
__device__ __forceinline__ float bfhi(unsigned p) { return __uint_as_float(p & 0xffff0000u); }
__device__ __forceinline__ float bflo(unsigned p) { return __uint_as_float(p << 16); }

__device__ __forceinline__ short8 cvt8(float4 v0, float4 v1) {
    ushort t[8] = { f2bf(v0.x), f2bf(v0.y), f2bf(v0.z), f2bf(v0.w),
                    f2bf(v1.x), f2bf(v1.y), f2bf(v1.z), f2bf(v1.w) };
    return *(short8*)t;
}

// ---------------- GEMM1 (blocks < t1) || bucket hist (blocks >= t1) --------
__global__ __launch_bounds__(512) void k_gemm1_hist(const float* __restrict__ h,
    const float* __restrict__ qw, const float* __restrict__ qb,
    ushort* __restrict__ nout, int nrows, int t1,
    const int* __restrict__ dst, int* __restrict__ hist, int nedges, int nb)
{
    __shared__ __align__(16) ushort aL[128 * 128];
    __shared__ __align__(16) ushort bL[128 * 128];
    const int tid = threadIdx.x;

    if (blockIdx.x >= t1) {
        // ---- bucket histogram: per-block LDS counters, bucket-major table
        int* hl = (int*)aL;                       // alias gemm LDS
        const int g = blockIdx.x - t1;
        const int G = gridDim.x - t1;
        for (int i = tid; i < nb; i += 512) hl[i] = 0;
        __syncthreads();
        const int chunk = (nedges + G - 1) / G;
        const int e0 = g * chunk, e1 = min(e0 + chunk, nedges);
        for (int e = e0 + tid; e < e1; e += 512)
            atomicAdd(&hl[dst[e] >> 6], 1);
        __syncthreads();
        for (int i = tid; i < nb; i += 512) hist[i * G + g] = hl[i];
        return;
    }

    // ---- GEMM1: 128-row tile, A+B in LDS
    const int rb = blockIdx.x * 128;
    const int rr = tid >> 4, sl = tid & 15;

    #pragma unroll
    for (int rg = 0; rg < 4; ++rg) {
        int row = rg * 32 + rr, gr = rb + row;
        float4 a0 = make_float4(0.f,0.f,0.f,0.f), a1 = a0;
        if (gr < nrows) {
            a0 = *(const float4*)&h[(size_t)gr * 128 + sl * 8];
            a1 = *(const float4*)&h[(size_t)gr * 128 + sl * 8 + 4];
        }
        *(short8*)&aL[row * 128 + (sl ^ (row & 7)) * 8] = cvt8(a0, a1);
        float4 b0 = *(const float4*)&qw[row * 128 + sl * 8];
        float4 b1 = *(const float4*)&qw[row * 128 + sl * 8 + 4];
        *(short8*)&bL[row * 128 + (sl ^ (row & 7)) * 8] = cvt8(b0, b1);
    }
    __syncthreads();

    const int w = tid >> 6, l = tid & 63;
    const int lr = l & 15, lk = l >> 4;
    const int row = w * 16 + lr;

    short8 a[4];
    #pragma unroll
    for (int ks = 0; ks < 4; ++ks)
        a[ks] = *(const short8*)&aL[row * 128 + ((ks * 4 + lk) ^ (lr & 7)) * 8];

    f32x4 acc[8];
    #pragma unroll
    for (int nt = 0; nt < 8; ++nt) acc[nt] = (f32x4){0.f, 0.f, 0.f, 0.f};

    #pragma unroll
    for (int nt = 0; nt < 8; ++nt)
        #pragma unroll
        for (int ks = 0; ks < 4; ++ks) {
            short8 b = *(const short8*)&bL[(nt * 16 + lr) * 128 + ((ks * 4 + lk) ^ (lr & 7)) * 8];
            acc[nt] = MFMA16(b, a[ks], acc[nt]);   // swapped: lane&15 = row
        }

    const int gr = rb + row;
    if (gr < nrows) {
        #pragma unroll
        for (int nt = 0; nt < 8; ++nt) {
            float4 bv = *(const float4*)&qb[nt * 16 + lk * 4];
            ushort t[4];
            t[0] = f2bf(fmaxf(acc[nt][0] + bv.x, 0.f));
            t[1] = f2bf(fmaxf(acc[nt][1] + bv.y, 0.f));
            t[2] = f2bf(fmaxf(acc[nt][2] + bv.z, 0.f));
            t[3] = f2bf(fmaxf(acc[nt][3] + bv.w, 0.f));
            *(ushort4*)&nout[(size_t)gr * 128 + nt * 16 + lk * 4] = *(ushort4*)t;
        }
    }
}

// ---------------- per-chunk exclusive scan over nb*G bins ------------------
__global__ __launch_bounds__(1024) void k_scan_blk(const int* __restrict__ counts,
    int* __restrict__ offs, int* __restrict__ partials, int n)
{
    __shared__ int wtot[16];
    const int tid = threadIdx.x, lane = tid & 63, wv = tid >> 6;
    const int idx = blockIdx.x * 1024 + tid;
    int v = (idx < n) ? counts[idx] : 0;
    int x = v;
    #pragma unroll
    for (int off = 1; off < 64; off <<= 1) {
        int y = __shfl_up(x, off);
        if (lane >= off) x += y;
    }
    if (lane == 63) wtot[wv] = x;
    __syncthreads();
    if (tid == 0) {
        int r = 0;
        #pragma unroll
        for (int q = 0; q < 16; ++q) { int t = wtot[q]; wtot[q] = r; r += t; }
    }
    __syncthreads();
    if (idx < n) offs[idx] = wtot[wv] + x - v;
    if (tid == 1023) partials[blockIdx.x] = wtot[15] + x;
}

// exclusive scan of <=128 chunk totals, one block of 128 threads
__global__ void k_scan_part(int* __restrict__ partials, int nb)
{
    __shared__ int wsum2[2];
    const int tid = threadIdx.x, lane = tid & 63, wv = tid >> 6;
    int v = (tid < nb) ? partials[tid] : 0;
    int x = v;
    #pragma unroll
    for (int off = 1; off < 64; off <<= 1) {
        int y = __shfl_up(x, off);
        if (lane >= off) x += y;
    }
    if (lane == 63) wsum2[wv] = x;
    __syncthreads();
    int add = (wv == 1) ? wsum2[0] : 0;
    if (tid < nb) partials[tid] = add + x - v;
}

// ---------------- partition: scatter into per-(bucket,block) bins ----------
// bin offset applied inline: binoff0[i] + parts[i>>10]  (scan_add deleted)
__global__ __launch_bounds__(256) void k_part(const int* __restrict__ src,
    const int* __restrict__ dst, const float* __restrict__ w,
    const int* __restrict__ binoff0, const int* __restrict__ parts,
    int2* __restrict__ eb, int nedges, int nb)
{
    __shared__ int cur[1024];
    const int g = blockIdx.x, tid = threadIdx.x, G = gridDim.x;
    for (int b = tid; b < nb; b += 256) {
        int i = b * G + g;
        cur[b] = binoff0[i] + parts[i >> 10];
    }
    __syncthreads();
    const int chunk = (nedges + G - 1) / G;
    const int e0 = g * chunk, e1 = min(e0 + chunk, nedges);
    for (int e = e0 + tid; e < e1; e += 256) {
        int d = dst[e];
        int pos = atomicAdd(&cur[d >> 6], 1);                // LDS cursor
        eb[pos] = make_int2(((d & 63) << 17) | src[e], __float_as_int(w[e]));
    }
}

// ---------------- bsort+gather fused: block = bucket of 64 dst rows --------
__global__ __launch_bounds__(256) void k_bsort_gather(const ushort* __restrict__ nsrc,
    const int2* __restrict__ eb, const int* __restrict__ binoff0,
    const int* __restrict__ parts, ushort* __restrict__ z2,
    int ndst, int nedges, int G, int NB)
{
    __shared__ int2 els[EDGE_CAP];    // 32 KB sorted edge run
    __shared__ int  base[65];
    __shared__ int  cur[64];
    const int b = blockIdx.x, tid = threadIdx.x;
    const int i0 = b * G;
    const int j0 = binoff0[i0] + parts[i0 >> 10];
    int j1 = nedges;
    if (b != NB - 1) {
        int i1 = (b + 1) * G;
        j1 = binoff0[i1] + parts[i1 >> 10];
    }
    const int cnt_e = j1 - j0;

    if (tid < 64) cur[tid] = 0;
    __syncthreads();
    for (int j = j0 + tid; j < j1; j += 256)
        atomicAdd(&cur[eb[j].x >> 17], 1);
    __syncthreads();

    if (tid < 64) {                    // wave 0: exclusive scan of 64 counters
        int a = cur[tid];
        int x = a;
        #pragma unroll
        for (int off = 1; off < 64; off <<= 1) {
            int y = __shfl_up(x, off);
            if (tid >= off) x += y;
        }
        base[tid] = x - a;
        cur[tid]  = x - a;
        if (tid == 63) base[64] = x;
    }
    __syncthreads();

    const int wv = tid >> 6, lane = tid & 63;
    const int g = lane >> 4, s = lane & 15;

    if (cnt_e <= EDGE_CAP) {
        // sort the run into LDS
        for (int j = j0 + tid; j < j1; j += 256) {
            int2 e = eb[j];
            int pos = atomicAdd(&cur[e.x >> 17], 1);
            els[pos] = make_int2(e.x & 0x1FFFF, e.y);
        }
        __syncthreads();

        // gather: wave wv handles local rows wv, wv+4, ... (16 rows)
        for (int r = wv; r < 64; r += 4) {
            int gr = b * 64 + r;
            if (gr >= ndst) break;
            const int ja = base[r], jb = base[r + 1];
            float acc[8] = {0.f,0.f,0.f,0.f,0.f,0.f,0.f,0.f};
            float ws = 0.f;
            for (int j = ja + g; j < jb; j += 4) {
                int2 ew = els[j];
                float we = __int_as_float(ew.y);
                short8 rv = *(const short8*)&nsrc[(size_t)ew.x * 128 + s * 8];
                uint4 p = __builtin_bit_cast(uint4, rv);
                acc[0] = fmaf(bflo(p.x), we, acc[0]);
                acc[1] = fmaf(bfhi(p.x), we, acc[1]);
                acc[2] = fmaf(bflo(p.y), we, acc[2]);
                acc[3] = fmaf(bfhi(p.y), we, acc[3]);
                acc[4] = fmaf(bflo(p.z), we, acc[4]);
                acc[5] = fmaf(bfhi(p.z), we, acc[5]);
                acc[6] = fmaf(bflo(p.w), we, acc[6]);
                acc[7] = fmaf(bfhi(p.w), we, acc[7]);
                ws += we;
            }
            #pragma unroll
            for (int i = 0; i < 8; ++i) {
                acc[i] += __shfl_xor(acc[i], 16);
                acc[i] += __shfl_xor(acc[i], 32);
            }
            ws += __shfl_xor(ws, 16);
            ws += __shfl_xor(ws, 32);
            if (g == 0) {
                float inv = 1.f / fmaxf(ws, 1.f);
                ushort t8[8];
                #pragma unroll
                for (int i = 0; i < 8; ++i) t8[i] = f2bf(acc[i] * inv);
                *(short8*)&z2[(size_t)gr * 128 + s * 8] = *(short8*)t8;
            }
        }
    } else {
        // fallback (never triggers for this input; correctness only):
        // scan the whole unsorted run per row, filtering by dst_local
        for (int r = wv; r < 64; r += 4) {
            int gr = b * 64 + r;
            if (gr >= ndst) break;
            float acc[8] = {0.f,0.f,0.f,0.f,0.f,0.f,0.f,0.f};
            float ws = 0.f;
            for (int j = j0 + g; j < j1; j += 4) {
                int2 e = eb[j];
                if ((e.x >> 17) != r) continue;
                float we = __int_as_float(e.y);
                short8 rv = *(const short8*)&nsrc[(size_t)(e.x & 0x1FFFF) * 128 + s * 8];
                uint4 p = __builtin_bit_cast(uint4, rv);
                acc[0] = fmaf(bflo(p.x), we, acc[0]);
                acc[1] = fmaf(bfhi(p.x), we, acc[1]);
                acc[2] = fmaf(bflo(p.y), we, acc[2]);
                acc[3] = fmaf(bfhi(p.y), we, acc[3]);
                acc[4] = fmaf(bflo(p.z), we, acc[4]);
                acc[5] = fmaf(bfhi(p.z), we, acc[5]);
                acc[6] = fmaf(bflo(p.w), we, acc[6]);
                acc[7] = fmaf(bfhi(p.w), we, acc[7]);
                ws += we;
            }
            #pragma unroll
            for (int i = 0; i < 8; ++i) {
                acc[i] += __shfl_xor(acc[i], 16);
                acc[i] += __shfl_xor(acc[i], 32);
            }
            ws += __shfl_xor(ws, 16);
            ws += __shfl_xor(ws, 32);
            if (g == 0) {
                float inv = 1.f / fmaxf(ws, 1.f);
                ushort t8[8];
                #pragma unroll
                for (int i = 0; i < 8; ++i) t8[i] = f2bf(acc[i] * inv);
                *(short8*)&z2[(size_t)gr * 128 + s * 8] = *(short8*)t8;
            }
        }
    }
}

// ---------------- GEMM2 + rownorm: 512 thr, 128-row tile, 2 K-phases -------
__global__ __launch_bounds__(512) void k_gemm2(const float* __restrict__ h,
    const ushort* __restrict__ z2, const float* __restrict__ ww,
    const float* __restrict__ wb, float* __restrict__ out, int nrows)
{
    __shared__ __align__(16) ushort aL[128 * 128];
    __shared__ __align__(16) ushort bL[128 * 128];
    const int tid = threadIdx.x;
    const int rb  = blockIdx.x * 128;
    const int rr = tid >> 4, sl = tid & 15;

    const int w = tid >> 6, l = tid & 63;
    const int lr = l & 15, lk = l >> 4;
    const int row = w * 16 + lr;

    f32x4 acc[8];
    #pragma unroll
    for (int nt = 0; nt < 8; ++nt) acc[nt] = (f32x4){0.f, 0.f, 0.f, 0.f};

    #pragma unroll
    for (int ph = 0; ph < 2; ++ph) {
        if (ph) __syncthreads();
        #pragma unroll
        for (int rg = 0; rg < 4; ++rg) {
            int r2 = rg * 32 + rr, gr = rb + r2;
            short8 av = (short8){0,0,0,0,0,0,0,0};
            if (gr < nrows) {
                if (ph == 0) {
                    float4 a0 = *(const float4*)&h[(size_t)gr * 128 + sl * 8];
                    float4 a1 = *(const float4*)&h[(size_t)gr * 128 + sl * 8 + 4];
                    av = cvt8(a0, a1);
                } else {
                    av = *(const short8*)&z2[(size_t)gr * 128 + sl * 8];
                }
            }
            *(short8*)&aL[r2 * 128 + (sl ^ (r2 & 7)) * 8] = av;
            float4 b0 = *(const float4*)&ww[r2 * 256 + ph * 128 + sl * 8];
            float4 b1 = *(const float4*)&ww[r2 * 256 + ph * 128 + sl * 8 + 4];
            *(short8*)&bL[r2 * 128 + (sl ^ (r2 & 7)) * 8] = cvt8(b0, b1);
        }
        __syncthreads();

        short8 a[4];
        #pragma unroll
        for (int ks = 0; ks < 4; ++ks)
            a[ks] = *(const short8*)&aL[row * 128 + ((ks * 4 + lk) ^ (lr & 7)) * 8];

        #pragma unroll
        for (int nt = 0; nt < 8; ++nt)
            #pragma unroll
            for (int ks = 0; ks < 4; ++ks) {
                short8 b = *(const short8*)&bL[(nt * 16 + lr) * 128 + ((ks * 4 + lk) ^ (lr & 7)) * 8];
                acc[nt] = MFMA16(b, a[ks], acc[nt]);
            }
    }

    float val[8][4];
    float ss = 0.f;
    #pragma unroll
    for (int nt = 0; nt < 8; ++nt) {
        float4 bv = *(const float4*)&wb[nt * 16 + lk * 4];
        #pragma unroll
        for (int v = 0; v < 4; ++v) {
            float x = acc[nt][v] + ((const float*)&bv)[v];
            x = fmaxf(x, 0.f);
            val[nt][v] = x;
            ss = fmaf(x, x, ss);
        }
    }
    ss += __shfl_xor(ss, 16);
    ss += __shfl_xor(ss, 32);
    float nr = sqrtf(ss);
    nr = (nr == 0.f) ? 1.f : nr;
    float inv = 1.f / nr;

    const int gr = rb + row;
    if (gr < nrows) {
        #pragma unroll
        for (int nt = 0; nt < 8; ++nt) {
            float4 o;
            o.x = val[nt][0] * inv; o.y = val[nt][1] * inv;
            o.z = val[nt][2] * inv; o.w = val[nt][3] * inv;
            *(float4*)&out[(size_t)gr * 128 + nt * 16 + lk * 4] = o;
        }
    }
}

// ---------------------------------------------------------------------------
extern "C" void kernel_launch(void* const* d_in, const int* in_sizes, int n_in,
                              void* d_out, int out_size, void* d_ws, size_t ws_size,
                              hipStream_t stream)
{
    const float* h   = (const float*)d_in[0];
    const float* wts = (const float*)d_in[1];
    const int*   src = (const int*)d_in[2];
    const int*   dst = (const int*)d_in[3];
    const float* qw  = (const float*)d_in[5];
    const float* qb  = (const float*)d_in[6];
    const float* www = (const float*)d_in[7];
    const float* wb  = (const float*)d_in[8];
    float* out = (float*)d_out;

    const int n_src   = in_sizes[0] / 128;
    const int n_edges = in_sizes[1];
    const int n_dst   = out_size / 128;

    const int G  = 128;                           // partition blocks
    const int NB = (n_dst + 63) / 64;             // buckets of 64 dst rows (782)
    const int NBINS = NB * G;                     // bin table (100096)

    // workspace layout
    ushort* nbuf    = (ushort*)d_ws;                         // n_src*128 bf16
    ushort* z2      = nbuf + (size_t)n_src * 128;            // n_dst*128 bf16
    int2*   eb      = (int2*)(z2 + (size_t)n_dst * 128);     // n_edges int2
    int*    hist    = (int*)(eb + n_edges);                  // NBINS
    int*    binoff0 = hist + NBINS;                          // NBINS
    int*    parts   = binoff0 + NBINS;                       // <= 128

    const int t1 = (n_src + 127) / 128;
    k_gemm1_hist<<<t1 + G, 512, 0, stream>>>(h, qw, qb, nbuf, n_src, t1,
                                             dst, hist, n_edges, NB);

    const int nbs = (NBINS + 1023) / 1024;        // 98
    k_scan_blk<<<nbs, 1024, 0, stream>>>(hist, binoff0, parts, NBINS);
    k_scan_part<<<1, 128, 0, stream>>>(parts, nbs);

    k_part<<<G, 256, 0, stream>>>(src, dst, wts, binoff0, parts, eb, n_edges, NB);

    k_bsort_gather<<<NB, 256, 0, stream>>>(nbuf, eb, binoff0, parts, z2,
                                           n_dst, n_edges, G, NB);

    const int t2 = (n_dst + 127) / 128;
    k_gemm2<<<t2, 512, 0, stream>>>(h, z2, www, wb, out, n_dst);
}